// Round 9
// baseline (118.785 us; speedup 1.0000x reference)
//
#include <hip/hip_runtime.h>
#include <math.h>

// Problem dims (fixed by setup_inputs)
#define B_LAB 1024
#define B_TOT 2048
#define CDIM  1024
#define DDIM  784
#define DPAD  832      // 784 padded to multiple of 64
#define H1DIM 512
#define H2DIM 128

#define SEM_BLOCKS 1024   // dim3(16, 32, 2)

typedef __attribute__((ext_vector_type(8))) __bf16 bf16x8;
typedef __attribute__((ext_vector_type(4))) float f32x4;
typedef __attribute__((ext_vector_type(8))) unsigned short ushort8;

// ---------------------------------------------------------------------------
// Workspace layout (byte offsets). Peak = 13,516,808 B (round-4 proven).
// ---------------------------------------------------------------------------
#define OFF_XB    0u
#define OFF_W1B   3407872u
#define OFF_H1B   4259840u
#define OFF_LPB   0u
#define OFF_L1PB  4194304u
#define OFF_MAB   8388608u
#define OFF_MNB   10485760u
#define OFF_W2B   12582912u
#define OFF_W3B   12713984u
#define OFF_H2B   12976128u
#define OFF_ROWS  13500416u

__device__ __forceinline__ unsigned short f2bf(float f) {
    unsigned int u = __builtin_bit_cast(unsigned int, f);
    u = (u + 0x7fff + ((u >> 16) & 1)) >> 16;   // RNE
    return (unsigned short)u;
}

__device__ __forceinline__ void gload_lds16(const void* g, void* l) {
    __builtin_amdgcn_global_load_lds(
        (const __attribute__((address_space(1))) unsigned int*)g,
        (__attribute__((address_space(3))) unsigned int*)l, 16, 0, 0);
}

// ---------------------------------------------------------------------------
// Fused prep (round-4 verified): counts + fp32->bf16 conversions + zeroing
// (rows1, rows2, ce accumulator, sem completion counter).
// ---------------------------------------------------------------------------
__global__ __launch_bounds__(256) void prep(
    const int* __restrict__ aidx, const int* __restrict__ nidx,
    const float* __restrict__ x, const float* __restrict__ xu,
    const float* __restrict__ W1, const float* __restrict__ W2,
    const float* __restrict__ W3,
    unsigned short* __restrict__ Mab, unsigned short* __restrict__ Mnb,
    unsigned short* __restrict__ XB, unsigned short* __restrict__ W1B,
    unsigned short* __restrict__ W2B, unsigned short* __restrict__ W3B,
    float* __restrict__ zero_base)
{
    __shared__ int cnt[2 * CDIM];
    const int bid = blockIdx.x, tid = threadIdx.x;

    if (bid < 1024) {
        const int i = bid;
        for (int j = tid; j < 2 * CDIM; j += 256) cnt[j] = 0;
        __syncthreads();
        if (tid < 32)       atomicAdd(&cnt[aidx[i * 32 + tid]], 1);
        else if (tid < 96)  atomicAdd(&cnt[CDIM + nidx[i * 64 + (tid - 32)]], 1);
        __syncthreads();
        for (int j = tid; j < CDIM; j += 256) {
            Mab[(size_t)i * CDIM + j] = f2bf((float)cnt[j]);
            Mnb[(size_t)i * CDIM + j] = f2bf((float)cnt[CDIM + j]);
        }
        return;
    }
    if (bid < 2160) {
        const float* src; unsigned short* dst; int K, cpr, chunk;
        if (bid < 1856) {
            int b = bid - 1024;
            bool lab = (b < 416);
            src = lab ? x : xu;
            dst = XB + (lab ? (size_t)0 : (size_t)B_LAB * DPAD);
            K = DDIM; cpr = 104;
            chunk = (lab ? b : b - 416) * 256 + tid;
        } else if (bid < 2064) {
            src = W1; dst = W1B; K = DDIM; cpr = 104;
            chunk = (bid - 1856) * 256 + tid;
        } else if (bid < 2096) {
            src = W2; dst = W2B; K = H1DIM; cpr = 64;
            chunk = (bid - 2064) * 256 + tid;
        } else {
            src = W3; dst = W3B; K = H2DIM; cpr = 16;
            chunk = (bid - 2096) * 256 + tid;
        }
        int row = chunk / cpr;
        int col = (chunk - row * cpr) * 8;
        int Kp  = cpr * 8;
        ushort8 o = {};
        if (col < K) {
            const float4* s = (const float4*)(src + (size_t)row * K + col);
            float4 a = s[0], b4 = s[1];
            o[0] = f2bf(a.x);  o[1] = f2bf(a.y);  o[2] = f2bf(a.z);  o[3] = f2bf(a.w);
            o[4] = f2bf(b4.x); o[5] = f2bf(b4.y); o[6] = f2bf(b4.z); o[7] = f2bf(b4.w);
        }
        *(ushort8*)(dst + (size_t)row * Kp + col) = o;
        return;
    }
    // zero: rows1(2048)+rows2(2048)+ce+counter = 4098 floats
    int base = (bid - 2160) * 2048 + tid * 8;
    #pragma unroll
    for (int k = 0; k < 8; ++k) {
        int j = base + k;
        if (j < 2 * B_TOT + 2) zero_base[j] = 0.f;
    }
}

// ---------------------------------------------------------------------------
// bf16 MFMA GEMM (round-4/6 verified): 64x64 tile, BK=64, 4 waves,
// 2-phase dbuf (2x16 KB LDS -> 4 blocks/CU), XOR-swizzled LDS.
// ---------------------------------------------------------------------------
template <int RELU>
__global__ __launch_bounds__(256) void mfma_gemm(
    const unsigned short* __restrict__ A, const unsigned short* __restrict__ W,
    const float* __restrict__ bias, unsigned short* __restrict__ out,
    int M, int N, int K)
{
    __shared__ __align__(16) char smem[2][16384];

    const int tid  = threadIdx.x;
    const int lane = tid & 63;
    const int w    = tid >> 6;
    const int wr   = w >> 1, wc = w & 1;
    const int lr   = lane & 15, lg = lane >> 4;
    const int m0   = blockIdx.y * 64;
    const int n0   = blockIdx.x * 64;
    const int NT   = K >> 6;

    f32x4 acc[2][2] = {};

    auto stage = [&](int b, int kt) {
        char* As = smem[b];
        char* Bs = smem[b] + 8192;
        #pragma unroll
        for (int l = 0; l < 2; ++l) {
            int d   = (l * 256 + tid) << 4;
            int row = d >> 7;
            int e   = d ^ ((row & 7) << 4);
            int col = (e & 127) >> 1;
            gload_lds16(A + (size_t)(m0 + row) * K + kt * 64 + col, As + d);
            gload_lds16(W + (size_t)(n0 + row) * K + kt * 64 + col, Bs + d);
        }
    };

    stage(0, 0);
    __syncthreads();

    int cur = 0;
    for (int kt = 0; kt < NT; ++kt) {
        if (kt + 1 < NT) stage(cur ^ 1, kt + 1);
        char* As = smem[cur];
        char* Bs = smem[cur] + 8192;
        #pragma unroll
        for (int ks = 0; ks < 2; ++ks) {
            bf16x8 af[2], bfv[2];
            #pragma unroll
            for (int mi = 0; mi < 2; ++mi) {
                int r = wr * 32 + mi * 16 + lr;
                af[mi] = *(const bf16x8*)(As + r * 128 +
                          ((ks * 64 + lg * 16) ^ ((r & 7) << 4)));
            }
            #pragma unroll
            for (int ni = 0; ni < 2; ++ni) {
                int r = wc * 32 + ni * 16 + lr;
                bfv[ni] = *(const bf16x8*)(Bs + r * 128 +
                          ((ks * 64 + lg * 16) ^ ((r & 7) << 4)));
            }
            #pragma unroll
            for (int mi = 0; mi < 2; ++mi)
                #pragma unroll
                for (int ni = 0; ni < 2; ++ni)
                    acc[mi][ni] = __builtin_amdgcn_mfma_f32_16x16x32_bf16(
                        af[mi], bfv[ni], acc[mi][ni], 0, 0, 0);
        }
        __syncthreads();
        cur ^= 1;
    }

    #pragma unroll
    for (int mi = 0; mi < 2; ++mi)
        #pragma unroll
        for (int r = 0; r < 4; ++r) {
            int m = m0 + wr * 32 + mi * 16 + lg * 4 + r;
            #pragma unroll
            for (int ni = 0; ni < 2; ++ni) {
                int n = n0 + wc * 32 + ni * 16 + lr;
                float v = acc[mi][ni][r] + bias[n];
                if (RELU) v = fmaxf(v, 0.f);
                out[(size_t)m * N + n] = f2bf(v);
            }
        }
}

// ---------------------------------------------------------------------------
// Layer 3 fused (64-sq + softplus identity), round-6 verified, NOW WITH
// LDS-staged coalesced output writes: the scattered 2B stores of LP/L1P are
// replaced by tile staging into the (dead) K-loop LDS buffers and ushort8
// global stores (16B/lane fully coalesced).
// ---------------------------------------------------------------------------
__global__ __launch_bounds__(256) void gemm3_fused(
    const unsigned short* __restrict__ A, const unsigned short* __restrict__ W,
    const float* __restrict__ bias, const int* __restrict__ y,
    unsigned short* __restrict__ LPb, unsigned short* __restrict__ L1Pb,
    float* __restrict__ ce_acc)
{
    __shared__ __align__(16) char smem[2][16384];
    __shared__ float part[4];

    const int tid  = threadIdx.x;
    const int lane = tid & 63;
    const int w    = tid >> 6;
    const int wr   = w >> 1, wc = w & 1;
    const int lr   = lane & 15, lg = lane >> 4;
    const int m0   = blockIdx.y * 64;
    const int n0   = blockIdx.x * 64;
    const int NT   = H2DIM >> 6;   // 2

    f32x4 acc[2][2] = {};

    auto stage = [&](int b, int kt) {
        char* As = smem[b];
        char* Bs = smem[b] + 8192;
        #pragma unroll
        for (int l = 0; l < 2; ++l) {
            int d   = (l * 256 + tid) << 4;
            int row = d >> 7;
            int e   = d ^ ((row & 7) << 4);
            int col = (e & 127) >> 1;
            gload_lds16(A + (size_t)(m0 + row) * H2DIM + kt * 64 + col, As + d);
            gload_lds16(W + (size_t)(n0 + row) * H2DIM + kt * 64 + col, Bs + d);
        }
    };

    stage(0, 0);
    __syncthreads();

    int cur = 0;
    for (int kt = 0; kt < NT; ++kt) {
        if (kt + 1 < NT) stage(cur ^ 1, kt + 1);
        char* As = smem[cur];
        char* Bs = smem[cur] + 8192;
        #pragma unroll
        for (int ks = 0; ks < 2; ++ks) {
            bf16x8 af[2], bfv[2];
            #pragma unroll
            for (int mi = 0; mi < 2; ++mi) {
                int r = wr * 32 + mi * 16 + lr;
                af[mi] = *(const bf16x8*)(As + r * 128 +
                          ((ks * 64 + lg * 16) ^ ((r & 7) << 4)));
            }
            #pragma unroll
            for (int ni = 0; ni < 2; ++ni) {
                int r = wc * 32 + ni * 16 + lr;
                bfv[ni] = *(const bf16x8*)(Bs + r * 128 +
                          ((ks * 64 + lg * 16) ^ ((r & 7) << 4)));
            }
            #pragma unroll
            for (int mi = 0; mi < 2; ++mi)
                #pragma unroll
                for (int ni = 0; ni < 2; ++ni)
                    acc[mi][ni] = __builtin_amdgcn_mfma_f32_16x16x32_bf16(
                        af[mi], bfv[ni], acc[mi][ni], 0, 0, 0);
        }
        __syncthreads();
        cur ^= 1;
    }

    // Epilogue: compute sp, CE; stage LP/L1P tiles into LDS (linear 64x64
    // ushort each), then write out coalesced.
    unsigned short* lp_t  = (unsigned short*)smem[0];   // 8 KB
    unsigned short* l1p_t = (unsigned short*)smem[1];   // 8 KB

    const bool lab = (m0 < B_LAB);
    float ce_local = 0.f;
    #pragma unroll
    for (int mi = 0; mi < 2; ++mi)
        #pragma unroll
        for (int r = 0; r < 4; ++r) {
            int mrow = wr * 32 + mi * 16 + lg * 4 + r;
            int tgt = lab ? y[m0 + mrow] : -1;
            #pragma unroll
            for (int ni = 0; ni < 2; ++ni) {
                int nloc = wc * 32 + ni * 16 + lr;
                float z  = acc[mi][ni][r] + bias[n0 + nloc];
                float sp = fmaxf(z, 0.f) + log1pf(expf(-fabsf(z)));
                lp_t[mrow * 64 + nloc]  = f2bf(z - sp);   // log(sigmoid(z))
                l1p_t[mrow * 64 + nloc] = f2bf(-sp);      // log(1-sigmoid(z))
                if (lab) ce_local += (nloc + n0 == tgt) ? (sp - z) : sp;
            }
        }
    __syncthreads();
    #pragma unroll
    for (int l = 0; l < 2; ++l) {
        int c   = l * 256 + tid;          // 0..511 chunks of 8 ushorts
        int row = c >> 3;                 // 64 rows
        int col = (c & 7) * 8;            // 8 chunks/row
        size_t g = (size_t)(m0 + row) * CDIM + n0 + col;
        *(ushort8*)(LPb + g)  = *(const ushort8*)(lp_t + row * 64 + col);
        *(ushort8*)(L1Pb + g) = *(const ushort8*)(l1p_t + row * 64 + col);
    }

    if (lab) {
        for (int off = 32; off; off >>= 1) ce_local += __shfl_down(ce_local, off);
        if ((tid & 63) == 0) part[tid >> 6] = ce_local;
        __syncthreads();
        if (tid == 0)
            atomicAdd(ce_acc, part[0] + part[1] + part[2] + part[3]);
    }
}

// ---------------------------------------------------------------------------
// Semantic-loss GEMM: EXACT round-6 structure (64x64, BK=64, 2x16 KB dbuf,
// grid (16,32,2) -> 4 blocks/CU) + fused finalize tail (completion counter;
// last block reduces rows -> out, saving one launch).
// ---------------------------------------------------------------------------
__global__ __launch_bounds__(256) void sem_gemm(
    const unsigned short* __restrict__ LPb, const unsigned short* __restrict__ L1Pb,
    const unsigned short* __restrict__ Mab, const unsigned short* __restrict__ Mnb,
    float* __restrict__ rows1, float* __restrict__ rows2,
    float* __restrict__ acc2 /* [0]=ce, [1]=counter */, float* __restrict__ out)
{
    __shared__ __align__(16) char smem[2][16384];
    __shared__ float part[4];
    __shared__ int lastflag;

    const unsigned short* Ag = (blockIdx.z == 0) ? LPb : L1Pb;
    const unsigned short* Bg = (blockIdx.z == 0) ? Mab : Mnb;
    float* rows = (blockIdx.z == 0) ? rows1 : rows2;

    const int tid  = threadIdx.x;
    const int lane = tid & 63;
    const int w    = tid >> 6;
    const int wr   = w >> 1, wc = w & 1;
    const int lr   = lane & 15, lg = lane >> 4;
    const int m0   = blockIdx.y * 64;
    const int n0   = blockIdx.x * 64;
    const int NT   = CDIM >> 6;   // 16

    f32x4 acc[2][2] = {};

    auto stage = [&](int b, int kt) {
        char* As = smem[b];
        char* Bs = smem[b] + 8192;
        #pragma unroll
        for (int l = 0; l < 2; ++l) {
            int d   = (l * 256 + tid) << 4;
            int row = d >> 7;
            int e   = d ^ ((row & 7) << 4);
            int col = (e & 127) >> 1;
            gload_lds16(Ag + (size_t)(m0 + row) * CDIM + kt * 64 + col, As + d);
            gload_lds16(Bg + (size_t)(n0 + row) * CDIM + kt * 64 + col, Bs + d);
        }
    };

    stage(0, 0);
    __syncthreads();

    int cur = 0;
    for (int kt = 0; kt < NT; ++kt) {
        if (kt + 1 < NT) stage(cur ^ 1, kt + 1);
        char* As = smem[cur];
        char* Bs = smem[cur] + 8192;
        #pragma unroll
        for (int ks = 0; ks < 2; ++ks) {
            bf16x8 af[2], bfv[2];
            #pragma unroll
            for (int mi = 0; mi < 2; ++mi) {
                int r = wr * 32 + mi * 16 + lr;
                af[mi] = *(const bf16x8*)(As + r * 128 +
                          ((ks * 64 + lg * 16) ^ ((r & 7) << 4)));
            }
            #pragma unroll
            for (int ni = 0; ni < 2; ++ni) {
                int r = wc * 32 + ni * 16 + lr;
                bfv[ni] = *(const bf16x8*)(Bs + r * 128 +
                          ((ks * 64 + lg * 16) ^ ((r & 7) << 4)));
            }
            #pragma unroll
            for (int mi = 0; mi < 2; ++mi)
                #pragma unroll
                for (int ni = 0; ni < 2; ++ni)
                    acc[mi][ni] = __builtin_amdgcn_mfma_f32_16x16x32_bf16(
                        af[mi], bfv[ni], acc[mi][ni], 0, 0, 0);
        }
        __syncthreads();
        cur ^= 1;
    }

    // Epilogue: exp(min(s,5)), reduce over n, one atomicAdd per m-row/wave.
    #pragma unroll
    for (int mi = 0; mi < 2; ++mi) {
        #pragma unroll
        for (int r = 0; r < 4; ++r) {
            float s = expf(fminf(acc[mi][0][r], 5.f))
                    + expf(fminf(acc[mi][1][r], 5.f));
            s += __shfl_xor(s, 1);
            s += __shfl_xor(s, 2);
            s += __shfl_xor(s, 4);
            s += __shfl_xor(s, 8);
            if (lr == 0) {
                int m = m0 + wr * 32 + mi * 16 + lg * 4 + r;
                atomicAdd(&rows[m], s);
            }
        }
    }

    // Fused finalize: last finishing block reduces rows -> out.
    __threadfence();
    if (tid == 0) {
        unsigned old = atomicAdd((unsigned int*)(acc2 + 1), 1u);
        lastflag = (old == SEM_BLOCKS - 1);
    }
    __syncthreads();
    if (!lastflag) return;

    float s = 0.f;
    for (int i = tid; i < B_TOT; i += 256) {
        float r1 = atomicAdd(&rows1[i], 0.f);   // device-coherent read
        float r2 = atomicAdd(&rows2[i], 0.f);
        s += -logf(fminf(r1, 1.f)) - logf(fminf(r2, 1.f));
    }
    for (int off = 32; off; off >>= 1) s += __shfl_down(s, off);
    if ((tid & 63) == 0) part[tid >> 6] = s;
    __syncthreads();
    if (tid == 0) {
        out[1] = (part[0] + part[1] + part[2] + part[3]) * (1.f / (float)B_LAB);
        out[0] = atomicAdd(acc2, 0.f) * (1.f / ((float)B_LAB * (float)CDIM));
    }
}

// ---------------------------------------------------------------------------
extern "C" void kernel_launch(void* const* d_in, const int* in_sizes, int n_in,
                              void* d_out, int out_size, void* d_ws, size_t ws_size,
                              hipStream_t stream)
{
    const float* x    = (const float*)d_in[0];
    const int*   y    = (const int*)  d_in[1];
    const float* xu   = (const float*)d_in[2];
    const int*   aidx = (const int*)  d_in[3];
    const int*   nidx = (const int*)  d_in[5];
    const float* W1 = (const float*)d_in[7];
    const float* b1 = (const float*)d_in[8];
    const float* W2 = (const float*)d_in[9];
    const float* b2 = (const float*)d_in[10];
    const float* W3 = (const float*)d_in[11];
    const float* b3 = (const float*)d_in[12];

    char* ws = (char*)d_ws;
    unsigned short* XB   = (unsigned short*)(ws + OFF_XB);
    unsigned short* W1B  = (unsigned short*)(ws + OFF_W1B);
    unsigned short* H1B  = (unsigned short*)(ws + OFF_H1B);
    unsigned short* LPb  = (unsigned short*)(ws + OFF_LPB);
    unsigned short* L1Pb = (unsigned short*)(ws + OFF_L1PB);
    unsigned short* MAB  = (unsigned short*)(ws + OFF_MAB);
    unsigned short* MNB  = (unsigned short*)(ws + OFF_MNB);
    unsigned short* W2B  = (unsigned short*)(ws + OFF_W2B);
    unsigned short* W3B  = (unsigned short*)(ws + OFF_W3B);
    unsigned short* H2B  = (unsigned short*)(ws + OFF_H2B);
    float* ROWS = (float*)(ws + OFF_ROWS);
    float* ACC  = ROWS + 2 * B_TOT;     // [0]=ce sum, [1]=sem completion counter
    float* out  = (float*)d_out;

    // all prep work in one launch (counts, conversions, zeroing incl. counter)
    prep<<<2163, 256, 0, stream>>>(aidx, nidx, x, xu, W1, W2, W3,
                                   MAB, MNB, XB, W1B, W2B, W3B, ROWS);

    // MLP on matrix cores, 64x64 tiles (high occupancy)
    mfma_gemm<1><<<dim3(H1DIM / 64, B_TOT / 64), 256, 0, stream>>>(
        XB, W1B, b1, H1B, B_TOT, H1DIM, DPAD);
    mfma_gemm<1><<<dim3(H2DIM / 64, B_TOT / 64), 256, 0, stream>>>(
        H1B, W2B, b2, H2B, B_TOT, H2DIM, H1DIM);
    gemm3_fused<<<dim3(CDIM / 64, B_TOT / 64), 256, 0, stream>>>(
        H2B, W3B, b3, y, LPb, L1Pb, ACC);

    // semantic loss GEMM (round-6 structure) + fused finalize
    sem_gemm<<<dim3(CDIM / 64, B_TOT / 64, 2), 256, 0, stream>>>(
        LPb, L1Pb, MAB, MNB, ROWS, ROWS + B_TOT, ACC, out);
}

// Round 10
// 61.570 us; speedup vs baseline: 1.9293x; 1.9293x over previous
//
#include <hip/hip_runtime.h>
#include <math.h>

// Problem dims (fixed by setup_inputs)
#define B_LAB 1024
#define B_TOT 2048
#define CDIM  1024
#define DDIM  784
#define DPAD  832      // 784 padded to multiple of 64
#define H1DIM 512
#define H2DIM 128

typedef __attribute__((ext_vector_type(8))) __bf16 bf16x8;
typedef __attribute__((ext_vector_type(4))) float f32x4;
typedef __attribute__((ext_vector_type(8))) unsigned short ushort8;

// ---------------------------------------------------------------------------
// Workspace layout (byte offsets). Peak = 13,516,808 B (round-4 proven).
// ---------------------------------------------------------------------------
#define OFF_XB    0u
#define OFF_W1B   3407872u
#define OFF_H1B   4259840u
#define OFF_LPB   0u
#define OFF_L1PB  4194304u
#define OFF_MAB   8388608u
#define OFF_MNB   10485760u
#define OFF_W2B   12582912u
#define OFF_W3B   12713984u
#define OFF_H2B   12976128u
#define OFF_ROWS  13500416u

__device__ __forceinline__ unsigned short f2bf(float f) {
    unsigned int u = __builtin_bit_cast(unsigned int, f);
    u = (u + 0x7fff + ((u >> 16) & 1)) >> 16;   // RNE
    return (unsigned short)u;
}

__device__ __forceinline__ void gload_lds16(const void* g, void* l) {
    __builtin_amdgcn_global_load_lds(
        (const __attribute__((address_space(1))) unsigned int*)g,
        (__attribute__((address_space(3))) unsigned int*)l, 16, 0, 0);
}

// ---------------------------------------------------------------------------
// Fused prep (round-4 verified): counts + fp32->bf16 conversions + zeroing.
// ---------------------------------------------------------------------------
__global__ __launch_bounds__(256) void prep(
    const int* __restrict__ aidx, const int* __restrict__ nidx,
    const float* __restrict__ x, const float* __restrict__ xu,
    const float* __restrict__ W1, const float* __restrict__ W2,
    const float* __restrict__ W3,
    unsigned short* __restrict__ Mab, unsigned short* __restrict__ Mnb,
    unsigned short* __restrict__ XB, unsigned short* __restrict__ W1B,
    unsigned short* __restrict__ W2B, unsigned short* __restrict__ W3B,
    float* __restrict__ zero_base)
{
    __shared__ int cnt[2 * CDIM];
    const int bid = blockIdx.x, tid = threadIdx.x;

    if (bid < 1024) {
        const int i = bid;
        for (int j = tid; j < 2 * CDIM; j += 256) cnt[j] = 0;
        __syncthreads();
        if (tid < 32)       atomicAdd(&cnt[aidx[i * 32 + tid]], 1);
        else if (tid < 96)  atomicAdd(&cnt[CDIM + nidx[i * 64 + (tid - 32)]], 1);
        __syncthreads();
        for (int j = tid; j < CDIM; j += 256) {
            Mab[(size_t)i * CDIM + j] = f2bf((float)cnt[j]);
            Mnb[(size_t)i * CDIM + j] = f2bf((float)cnt[CDIM + j]);
        }
        return;
    }
    if (bid < 2160) {
        const float* src; unsigned short* dst; int K, cpr, chunk;
        if (bid < 1856) {
            int b = bid - 1024;
            bool lab = (b < 416);
            src = lab ? x : xu;
            dst = XB + (lab ? (size_t)0 : (size_t)B_LAB * DPAD);
            K = DDIM; cpr = 104;
            chunk = (lab ? b : b - 416) * 256 + tid;
        } else if (bid < 2064) {
            src = W1; dst = W1B; K = DDIM; cpr = 104;
            chunk = (bid - 1856) * 256 + tid;
        } else if (bid < 2096) {
            src = W2; dst = W2B; K = H1DIM; cpr = 64;
            chunk = (bid - 2064) * 256 + tid;
        } else {
            src = W3; dst = W3B; K = H2DIM; cpr = 16;
            chunk = (bid - 2096) * 256 + tid;
        }
        int row = chunk / cpr;
        int col = (chunk - row * cpr) * 8;
        int Kp  = cpr * 8;
        ushort8 o = {};
        if (col < K) {
            const float4* s = (const float4*)(src + (size_t)row * K + col);
            float4 a = s[0], b4 = s[1];
            o[0] = f2bf(a.x);  o[1] = f2bf(a.y);  o[2] = f2bf(a.z);  o[3] = f2bf(a.w);
            o[4] = f2bf(b4.x); o[5] = f2bf(b4.y); o[6] = f2bf(b4.z); o[7] = f2bf(b4.w);
        }
        *(ushort8*)(dst + (size_t)row * Kp + col) = o;
        return;
    }
    int base = (bid - 2160) * 2048 + tid * 8;
    #pragma unroll
    for (int k = 0; k < 8; ++k) {
        int j = base + k;
        if (j < 2 * B_TOT + 2) zero_base[j] = 0.f;
    }
}

// ---------------------------------------------------------------------------
// bf16 MFMA GEMM (round-4/6 verified): 64x64 tile, BK=64, 4 waves,
// 2-phase dbuf (2x16 KB LDS -> 4 blocks/CU), XOR-swizzled LDS.
// ---------------------------------------------------------------------------
template <int RELU>
__global__ __launch_bounds__(256) void mfma_gemm(
    const unsigned short* __restrict__ A, const unsigned short* __restrict__ W,
    const float* __restrict__ bias, unsigned short* __restrict__ out,
    int M, int N, int K)
{
    __shared__ __align__(16) char smem[2][16384];

    const int tid  = threadIdx.x;
    const int lane = tid & 63;
    const int w    = tid >> 6;
    const int wr   = w >> 1, wc = w & 1;
    const int lr   = lane & 15, lg = lane >> 4;
    const int m0   = blockIdx.y * 64;
    const int n0   = blockIdx.x * 64;
    const int NT   = K >> 6;

    f32x4 acc[2][2] = {};

    auto stage = [&](int b, int kt) {
        char* As = smem[b];
        char* Bs = smem[b] + 8192;
        #pragma unroll
        for (int l = 0; l < 2; ++l) {
            int d   = (l * 256 + tid) << 4;
            int row = d >> 7;
            int e   = d ^ ((row & 7) << 4);
            int col = (e & 127) >> 1;
            gload_lds16(A + (size_t)(m0 + row) * K + kt * 64 + col, As + d);
            gload_lds16(W + (size_t)(n0 + row) * K + kt * 64 + col, Bs + d);
        }
    };

    stage(0, 0);
    __syncthreads();

    int cur = 0;
    for (int kt = 0; kt < NT; ++kt) {
        if (kt + 1 < NT) stage(cur ^ 1, kt + 1);
        char* As = smem[cur];
        char* Bs = smem[cur] + 8192;
        #pragma unroll
        for (int ks = 0; ks < 2; ++ks) {
            bf16x8 af[2], bfv[2];
            #pragma unroll
            for (int mi = 0; mi < 2; ++mi) {
                int r = wr * 32 + mi * 16 + lr;
                af[mi] = *(const bf16x8*)(As + r * 128 +
                          ((ks * 64 + lg * 16) ^ ((r & 7) << 4)));
            }
            #pragma unroll
            for (int ni = 0; ni < 2; ++ni) {
                int r = wc * 32 + ni * 16 + lr;
                bfv[ni] = *(const bf16x8*)(Bs + r * 128 +
                          ((ks * 64 + lg * 16) ^ ((r & 7) << 4)));
            }
            #pragma unroll
            for (int mi = 0; mi < 2; ++mi)
                #pragma unroll
                for (int ni = 0; ni < 2; ++ni)
                    acc[mi][ni] = __builtin_amdgcn_mfma_f32_16x16x32_bf16(
                        af[mi], bfv[ni], acc[mi][ni], 0, 0, 0);
        }
        __syncthreads();
        cur ^= 1;
    }

    #pragma unroll
    for (int mi = 0; mi < 2; ++mi)
        #pragma unroll
        for (int r = 0; r < 4; ++r) {
            int m = m0 + wr * 32 + mi * 16 + lg * 4 + r;
            #pragma unroll
            for (int ni = 0; ni < 2; ++ni) {
                int n = n0 + wc * 32 + ni * 16 + lr;
                float v = acc[mi][ni][r] + bias[n];
                if (RELU) v = fmaxf(v, 0.f);
                out[(size_t)m * N + n] = f2bf(v);
            }
        }
}

// ---------------------------------------------------------------------------
// Layer 3 fused (64-sq + softplus identity), round-6 verified, with the ONE
// round-10 change: LDS-staged coalesced LP/L1P writes (ushort8, stride-72
// padded rows to break bank conflicts) instead of scattered 2B stores.
// ---------------------------------------------------------------------------
__global__ __launch_bounds__(256) void gemm3_fused(
    const unsigned short* __restrict__ A, const unsigned short* __restrict__ W,
    const float* __restrict__ bias, const int* __restrict__ y,
    unsigned short* __restrict__ LPb, unsigned short* __restrict__ L1Pb,
    float* __restrict__ ce_acc)
{
    __shared__ __align__(16) char smem[2][16384];
    __shared__ float part[4];

    const int tid  = threadIdx.x;
    const int lane = tid & 63;
    const int w    = tid >> 6;
    const int wr   = w >> 1, wc = w & 1;
    const int lr   = lane & 15, lg = lane >> 4;
    const int m0   = blockIdx.y * 64;
    const int n0   = blockIdx.x * 64;
    const int NT   = H2DIM >> 6;   // 2

    f32x4 acc[2][2] = {};

    auto stage = [&](int b, int kt) {
        char* As = smem[b];
        char* Bs = smem[b] + 8192;
        #pragma unroll
        for (int l = 0; l < 2; ++l) {
            int d   = (l * 256 + tid) << 4;
            int row = d >> 7;
            int e   = d ^ ((row & 7) << 4);
            int col = (e & 127) >> 1;
            gload_lds16(A + (size_t)(m0 + row) * H2DIM + kt * 64 + col, As + d);
            gload_lds16(W + (size_t)(n0 + row) * H2DIM + kt * 64 + col, Bs + d);
        }
    };

    stage(0, 0);
    __syncthreads();

    int cur = 0;
    for (int kt = 0; kt < NT; ++kt) {
        if (kt + 1 < NT) stage(cur ^ 1, kt + 1);
        char* As = smem[cur];
        char* Bs = smem[cur] + 8192;
        #pragma unroll
        for (int ks = 0; ks < 2; ++ks) {
            bf16x8 af[2], bfv[2];
            #pragma unroll
            for (int mi = 0; mi < 2; ++mi) {
                int r = wr * 32 + mi * 16 + lr;
                af[mi] = *(const bf16x8*)(As + r * 128 +
                          ((ks * 64 + lg * 16) ^ ((r & 7) << 4)));
            }
            #pragma unroll
            for (int ni = 0; ni < 2; ++ni) {
                int r = wc * 32 + ni * 16 + lr;
                bfv[ni] = *(const bf16x8*)(Bs + r * 128 +
                          ((ks * 64 + lg * 16) ^ ((r & 7) << 4)));
            }
            #pragma unroll
            for (int mi = 0; mi < 2; ++mi)
                #pragma unroll
                for (int ni = 0; ni < 2; ++ni)
                    acc[mi][ni] = __builtin_amdgcn_mfma_f32_16x16x32_bf16(
                        af[mi], bfv[ni], acc[mi][ni], 0, 0, 0);
        }
        __syncthreads();
        cur ^= 1;
    }

    // Epilogue: compute sp + CE; stage LP/L1P in LDS (64 rows, stride 72
    // ushorts = 144 B, 16B-aligned), then ushort8 coalesced global writes.
    unsigned short* lp_t  = (unsigned short*)smem[0];   // 9216 B used
    unsigned short* l1p_t = (unsigned short*)smem[1];

    const bool lab = (m0 < B_LAB);
    float ce_local = 0.f;
    #pragma unroll
    for (int mi = 0; mi < 2; ++mi)
        #pragma unroll
        for (int r = 0; r < 4; ++r) {
            int mrow = wr * 32 + mi * 16 + lg * 4 + r;
            int tgt = lab ? y[m0 + mrow] : -1;
            #pragma unroll
            for (int ni = 0; ni < 2; ++ni) {
                int nloc = wc * 32 + ni * 16 + lr;
                float z  = acc[mi][ni][r] + bias[n0 + nloc];
                float sp = fmaxf(z, 0.f) + log1pf(expf(-fabsf(z)));
                lp_t[mrow * 72 + nloc]  = f2bf(z - sp);   // log(sigmoid(z))
                l1p_t[mrow * 72 + nloc] = f2bf(-sp);      // log(1-sigmoid(z))
                if (lab) ce_local += (nloc + n0 == tgt) ? (sp - z) : sp;
            }
        }
    __syncthreads();
    #pragma unroll
    for (int l = 0; l < 2; ++l) {
        int c   = l * 256 + tid;          // 512 chunks of 8 ushorts
        int row = c >> 3;
        int col = (c & 7) * 8;
        size_t g = (size_t)(m0 + row) * CDIM + n0 + col;
        *(ushort8*)(LPb + g)  = *(const ushort8*)(lp_t + row * 72 + col);
        *(ushort8*)(L1Pb + g) = *(const ushort8*)(l1p_t + row * 72 + col);
    }

    if (lab) {
        for (int off = 32; off; off >>= 1) ce_local += __shfl_down(ce_local, off);
        if ((tid & 63) == 0) part[tid >> 6] = ce_local;
        __syncthreads();
        if (tid == 0)
            atomicAdd(ce_acc, part[0] + part[1] + part[2] + part[3]);
    }
}

// ---------------------------------------------------------------------------
// Semantic-loss GEMM: EXACT round-6 structure (64x64, BK=64, 2x16 KB dbuf,
// grid (16,32,2) -> 4 blocks/CU). No fences, no fused tail.
// ---------------------------------------------------------------------------
__global__ __launch_bounds__(256) void sem_gemm(
    const unsigned short* __restrict__ LPb, const unsigned short* __restrict__ L1Pb,
    const unsigned short* __restrict__ Mab, const unsigned short* __restrict__ Mnb,
    float* __restrict__ rows1, float* __restrict__ rows2)
{
    __shared__ __align__(16) char smem[2][16384];

    const unsigned short* Ag = (blockIdx.z == 0) ? LPb : L1Pb;
    const unsigned short* Bg = (blockIdx.z == 0) ? Mab : Mnb;
    float* rows = (blockIdx.z == 0) ? rows1 : rows2;

    const int tid  = threadIdx.x;
    const int lane = tid & 63;
    const int w    = tid >> 6;
    const int wr   = w >> 1, wc = w & 1;
    const int lr   = lane & 15, lg = lane >> 4;
    const int m0   = blockIdx.y * 64;
    const int n0   = blockIdx.x * 64;
    const int NT   = CDIM >> 6;   // 16

    f32x4 acc[2][2] = {};

    auto stage = [&](int b, int kt) {
        char* As = smem[b];
        char* Bs = smem[b] + 8192;
        #pragma unroll
        for (int l = 0; l < 2; ++l) {
            int d   = (l * 256 + tid) << 4;
            int row = d >> 7;
            int e   = d ^ ((row & 7) << 4);
            int col = (e & 127) >> 1;
            gload_lds16(Ag + (size_t)(m0 + row) * CDIM + kt * 64 + col, As + d);
            gload_lds16(Bg + (size_t)(n0 + row) * CDIM + kt * 64 + col, Bs + d);
        }
    };

    stage(0, 0);
    __syncthreads();

    int cur = 0;
    for (int kt = 0; kt < NT; ++kt) {
        if (kt + 1 < NT) stage(cur ^ 1, kt + 1);
        char* As = smem[cur];
        char* Bs = smem[cur] + 8192;
        #pragma unroll
        for (int ks = 0; ks < 2; ++ks) {
            bf16x8 af[2], bfv[2];
            #pragma unroll
            for (int mi = 0; mi < 2; ++mi) {
                int r = wr * 32 + mi * 16 + lr;
                af[mi] = *(const bf16x8*)(As + r * 128 +
                          ((ks * 64 + lg * 16) ^ ((r & 7) << 4)));
            }
            #pragma unroll
            for (int ni = 0; ni < 2; ++ni) {
                int r = wc * 32 + ni * 16 + lr;
                bfv[ni] = *(const bf16x8*)(Bs + r * 128 +
                          ((ks * 64 + lg * 16) ^ ((r & 7) << 4)));
            }
            #pragma unroll
            for (int mi = 0; mi < 2; ++mi)
                #pragma unroll
                for (int ni = 0; ni < 2; ++ni)
                    acc[mi][ni] = __builtin_amdgcn_mfma_f32_16x16x32_bf16(
                        af[mi], bfv[ni], acc[mi][ni], 0, 0, 0);
        }
        __syncthreads();
        cur ^= 1;
    }

    // Epilogue: exp(min(s,5)), reduce over n, one atomicAdd per m-row/wave.
    #pragma unroll
    for (int mi = 0; mi < 2; ++mi) {
        #pragma unroll
        for (int r = 0; r < 4; ++r) {
            float s = expf(fminf(acc[mi][0][r], 5.f))
                    + expf(fminf(acc[mi][1][r], 5.f));
            s += __shfl_xor(s, 1);
            s += __shfl_xor(s, 2);
            s += __shfl_xor(s, 4);
            s += __shfl_xor(s, 8);
            if (lr == 0) {
                int m = m0 + wr * 32 + mi * 16 + lg * 4 + r;
                atomicAdd(&rows[m], s);
            }
        }
    }
}

// ---------------------------------------------------------------------------
__global__ __launch_bounds__(256) void final_kernel(
    const float* __restrict__ rows1, const float* __restrict__ rows2,
    const float* __restrict__ ce_acc, float* __restrict__ out)
{
    __shared__ float part[4];
    float s = 0.f;
    for (int i = threadIdx.x; i < B_TOT; i += 256)
        s += -logf(fminf(rows1[i], 1.f)) - logf(fminf(rows2[i], 1.f));
    for (int off = 32; off; off >>= 1) s += __shfl_down(s, off);
    if ((threadIdx.x & 63) == 0) part[threadIdx.x >> 6] = s;
    __syncthreads();
    if (threadIdx.x == 0) {
        out[1] = (part[0] + part[1] + part[2] + part[3]) * (1.f / (float)B_LAB);
        out[0] = ce_acc[0] * (1.f / ((float)B_LAB * (float)CDIM));
    }
}

// ---------------------------------------------------------------------------
extern "C" void kernel_launch(void* const* d_in, const int* in_sizes, int n_in,
                              void* d_out, int out_size, void* d_ws, size_t ws_size,
                              hipStream_t stream)
{
    const float* x    = (const float*)d_in[0];
    const int*   y    = (const int*)  d_in[1];
    const float* xu   = (const float*)d_in[2];
    const int*   aidx = (const int*)  d_in[3];
    const int*   nidx = (const int*)  d_in[5];
    const float* W1 = (const float*)d_in[7];
    const float* b1 = (const float*)d_in[8];
    const float* W2 = (const float*)d_in[9];
    const float* b2 = (const float*)d_in[10];
    const float* W3 = (const float*)d_in[11];
    const float* b3 = (const float*)d_in[12];

    char* ws = (char*)d_ws;
    unsigned short* XB   = (unsigned short*)(ws + OFF_XB);
    unsigned short* W1B  = (unsigned short*)(ws + OFF_W1B);
    unsigned short* H1B  = (unsigned short*)(ws + OFF_H1B);
    unsigned short* LPb  = (unsigned short*)(ws + OFF_LPB);
    unsigned short* L1Pb = (unsigned short*)(ws + OFF_L1PB);
    unsigned short* MAB  = (unsigned short*)(ws + OFF_MAB);
    unsigned short* MNB  = (unsigned short*)(ws + OFF_MNB);
    unsigned short* W2B  = (unsigned short*)(ws + OFF_W2B);
    unsigned short* W3B  = (unsigned short*)(ws + OFF_W3B);
    unsigned short* H2B  = (unsigned short*)(ws + OFF_H2B);
    float* ROWS = (float*)(ws + OFF_ROWS);
    float* ACC  = ROWS + 2 * B_TOT;
    float* out  = (float*)d_out;

    // all prep work in one launch (counts, conversions, zeroing)
    prep<<<2163, 256, 0, stream>>>(aidx, nidx, x, xu, W1, W2, W3,
                                   MAB, MNB, XB, W1B, W2B, W3B, ROWS);

    // MLP on matrix cores, 64x64 tiles (high occupancy)
    mfma_gemm<1><<<dim3(H1DIM / 64, B_TOT / 64), 256, 0, stream>>>(
        XB, W1B, b1, H1B, B_TOT, H1DIM, DPAD);
    mfma_gemm<1><<<dim3(H2DIM / 64, B_TOT / 64), 256, 0, stream>>>(
        H1B, W2B, b2, H2B, B_TOT, H2DIM, H1DIM);
    gemm3_fused<<<dim3(CDIM / 64, B_TOT / 64), 256, 0, stream>>>(
        H2B, W3B, b3, y, LPb, L1Pb, ACC);

    // semantic loss GEMM (round-6 structure, no tail)
    sem_gemm<<<dim3(CDIM / 64, B_TOT / 64, 2), 256, 0, stream>>>(
        LPb, L1Pb, MAB, MNB, ROWS, ROWS + B_TOT);
    final_kernel<<<1, 256, 0, stream>>>(ROWS, ROWS + B_TOT, ACC, out);
}